// Round 3
// baseline (421.387 us; speedup 1.0000x reference)
//
#include <hip/hip_runtime.h>
#include <cmath>
#include <stdint.h>

#define HH 64
#define WD 64
#define CIN 256
#define COUT 256
#define NB 32

typedef _Float16 half8 __attribute__((ext_vector_type(8)));
typedef _Float16 half4 __attribute__((ext_vector_type(4)));
typedef float floatx4 __attribute__((ext_vector_type(4)));
typedef float floatx16 __attribute__((ext_vector_type(16)));

#define SB() __builtin_amdgcn_sched_barrier(0)

__device__ __forceinline__ void glds16(const void* src, void* dst) {
    __builtin_amdgcn_global_load_lds((const __attribute__((address_space(1))) void*)src,
                                     (__attribute__((address_space(3))) void*)dst, 16, 0, 0);
}

// ---------------------------------------------------------------------------
// xprep: NCHW fp32 -> fp16 [n][chunk8][h64][w64][ci32]  (67 MB in ws)
// ---------------------------------------------------------------------------
__global__ __launch_bounds__(256) void xprep_kernel(const float* __restrict__ x,
                                                    _Float16* __restrict__ x16) {
    __shared__ _Float16 lt[32 * 72];
    const int tid = threadIdx.x;
    const int bid = blockIdx.x;           // n*512 + chunk*64 + h
    const int h = bid & 63;
    const int chunk = (bid >> 6) & 7;
    const int n = bid >> 9;
    {
        const int ci = tid >> 3;
        const int w8 = (tid & 7) * 8;
        const float* src = x + (((size_t)(n * 256 + chunk * 32 + ci) * 64 + h) * 64 + w8);
        const float4 a = *(const float4*)src;
        const float4 b = *(const float4*)(src + 4);
        half8 hv;
        hv[0] = (_Float16)a.x; hv[1] = (_Float16)a.y; hv[2] = (_Float16)a.z; hv[3] = (_Float16)a.w;
        hv[4] = (_Float16)b.x; hv[5] = (_Float16)b.y; hv[6] = (_Float16)b.z; hv[7] = (_Float16)b.w;
        *(half8*)&lt[ci * 72 + w8] = hv;
    }
    __syncthreads();
    {
        const int w = tid >> 2;
        const int kc = tid & 3;
        half8 hv;
        #pragma unroll
        for (int j = 0; j < 8; ++j) hv[j] = lt[(kc * 8 + j) * 72 + w];
        *(half8*)&x16[(((size_t)(n * 8 + chunk) * 64 + h) * 64 + w) * 32 + kc * 8] = hv;
    }
}

// ---------------------------------------------------------------------------
// wprep: w [co][ci][3][3] fp32 -> fp16 A-fragments for mfma 32x32x16:
// [chunk8][cb4][tap9][ks2][cob2][lane64][j8]
// co = cb*64 + cob*32 + (lane&31), ci = chunk*32 + ks*16 + (lane>>5)*8 + j.
// block 0 also zero-fills the 4KB zero page used for conv halo rows/cols.
// ---------------------------------------------------------------------------
__global__ __launch_bounds__(256) void wprep_kernel(const float* __restrict__ w,
                                                    _Float16* __restrict__ w16,
                                                    float4* __restrict__ zp) {
    const int idx = blockIdx.x * 256 + threadIdx.x;   // 589,824
    const int j    = idx & 7;
    const int lane = (idx >> 3) & 63;
    const int cob  = (idx >> 9) & 1;
    const int ks   = (idx >> 10) & 1;
    const int t2   = idx >> 11;          // 0..287
    const int tap  = t2 % 9;
    const int rr   = t2 / 9;             // 0..31
    const int cb   = rr & 3;
    const int chunk = rr >> 2;
    const int co = cb * 64 + cob * 32 + (lane & 31);
    const int ci = chunk * 32 + ks * 16 + (lane >> 5) * 8 + j;
    w16[idx] = (_Float16)w[(co * CIN + ci) * 9 + tap];
    if (blockIdx.x == 0) {
        float4 z; z.x = 0.f; z.y = 0.f; z.z = 0.f; z.w = 0.f;
        zp[threadIdx.x] = z;   // 4 KB of zeros
    }
}

// ---------------------------------------------------------------------------
// gprep1: per-channel circulant generators -> gtab[c][isv][r] fp32
// all phases are exact multiples of 2*pi/64 -> v_sin/v_cos on revolutions
// ---------------------------------------------------------------------------
__global__ __launch_bounds__(256) void gprep1_kernel(const float* __restrict__ alpha,
                                                     float* __restrict__ gtab) {
    const int gid = blockIdx.x * 256 + threadIdx.x;     // 32,768
    const int r   = gid & 63;
    const int isv = (gid >> 6) & 1;
    const int c   = gid >> 7;
    const float t0 = tanhf(alpha[c * 4 + isv * 2 + 0]);
    const float t1 = tanhf(alpha[c * 4 + isv * 2 + 1]);
    const float qq = 0.70710678118654752f;
    const float a0 = qq * (t0 + t1);   // tap -1
    const float a2 = qq * (t1 - t0);   // tap +1
    const float rev = 0.015625f;       // 1/64 revolution
    float ssum = 0.f;
    for (int p = 0; p < 64; ++p) {
        const float pr = (float)p * rev;
        const float re = 1.f + (a0 + a2) * __builtin_amdgcn_cosf(pr);
        const float im = (a0 - a2) * __builtin_amdgcn_sinf(pr);
        const float inv = 1.f / (re * re + im * im);
        const float ph = (float)((p * r) & 63) * rev;
        ssum += (__builtin_amdgcn_cosf(ph) * re + __builtin_amdgcn_sinf(ph) * im) * inv;
    }
    gtab[gid] = ssum * (1.0f / 64.0f);
}

// ---------------------------------------------------------------------------
// gprep2: expand to swizzled fp16 circulant matrices
// gm[c][which2][row64][kc8 ^ (row&7)][8],  G[row][col] = g[(row-col)&63]
// ---------------------------------------------------------------------------
__global__ __launch_bounds__(256) void gprep2_kernel(const float* __restrict__ gtab,
                                                     _Float16* __restrict__ gm) {
    const int idx = blockIdx.x * 256 + threadIdx.x;  // 262,144
    const int kc = idx & 7;
    const int row = (idx >> 3) & 63;
    const int which = (idx >> 9) & 1;
    const int c = idx >> 10;
    const float* g = gtab + c * 128 + which * 64;
    half8 hv;
    #pragma unroll
    for (int j = 0; j < 8; ++j)
        hv[j] = (_Float16)g[(row - (kc * 8 + j)) & 63];
    *(half8*)&gm[((size_t)(c * 2 + which) * 64 + row) * 64 + ((kc ^ (row & 7)) * 8)] = hv;
}

// ---------------------------------------------------------------------------
// Conv 3x3 as implicit GEMM, fp16 MFMA 32x32x16 (2495 TF ceiling vs 2176).
// 256-thread block (4 waves), tile 64co x 16rows x 32cols.
// Wave: 64co x 4rows x 32px = 2 cob x 4 ro tiles of 32x32 (acc 8 x floatx16
// = 128 AGPR). ky-row-reuse: 6 staged rows feed 12 (ro,ky) pairs.
// LDS tile [row18][oct4][col34] x 16B: a 32-wide B-fragment read is two
// contiguous 512B runs -> conflict-free; staging is linear global_load_lds.
// LDS dbuf 2x39,168B -> 2 blocks/CU (barrier-decoupled); staging issued early
// inside compute; one barrier per chunk; setprio around MFMA clusters.
// Output fp16 into upper half of each plane's fp32 slot in d_out.
// ---------------------------------------------------------------------------
__global__ __launch_bounds__(256, 2) void conv_mfma(const _Float16* __restrict__ x16,
                                                    const _Float16* __restrict__ w16,
                                                    const _Float16* __restrict__ zp,
                                                    float* __restrict__ y) {
    extern __shared__ __align__(16) _Float16 xs2[];   // 2 * 19,584 halfs = 78,336 B
    const int tid  = threadIdx.x;
    const int lane = tid & 63;
    const int wv   = tid >> 6;          // 0..3
    const int l31  = lane & 31;
    const int kh   = lane >> 5;

    // XCD-bijective remap: the 8 (cb,wt) blocks of one (n,ht) land on one XCD.
    const int bid  = blockIdx.x;        // 1024
    const int xcd  = bid & 7;
    const int idx  = bid >> 3;          // 0..127
    const int sub  = idx & 7;
    const int cb   = sub >> 1;          // 0..3
    const int wt   = sub & 1;           // 0..1
    const int pair = xcd * 16 + (idx >> 3);   // 0..127 = (ht,n)
    const int ht   = pair & 3;
    const int n    = pair >> 2;
    const int h0   = ht * 16;
    const int w0   = wt * 32;

    // staging: 2448 slots of 16B; slot = row*136 + oct*34 + col (rows 18,
    // octs 4, cols 34); data = x[h0-1+row][w0-1+col][oct*8 .. +8]  (linear)
    int soff[10];
    #pragma unroll
    for (int it = 0; it < 10; ++it) {
        const int slot = it * 256 + tid;
        const int row  = (slot * 7711) >> 20;        // floor(slot/136), slot<2448
        const int rem  = slot - row * 136;
        const int oct  = (rem * 241) >> 13;          // floor(rem/34), rem<136
        const int col  = rem - oct * 34;
        const int gh   = h0 - 1 + row;
        const int gw   = w0 - 1 + col;
        soff[it] = ((unsigned)gh < 64u && (unsigned)gw < 64u)
                 ? ((gh * 64 + gw) * 32 + oct * 8) : -1;
    }

    // per-lane B-fragment base (halfs): kh selects upper k-half row, l31 = px
    const int albase = (kh * 34 + l31) * 8;

    floatx16 acc[4][2];
    #pragma unroll
    for (int ro = 0; ro < 4; ++ro)
        #pragma unroll
        for (int cob = 0; cob < 2; ++cob) acc[ro][cob] = (floatx16)0.f;

    // prologue: stage chunk 0 into buffer 0
    {
        const _Float16* xc0 = x16 + (size_t)n * 1048576;
        #pragma unroll
        for (int it = 0; it < 10; ++it) {
            if (it * 256 + tid < 2448) {
                const _Float16* src = (soff[it] >= 0) ? xc0 + soff[it] : zp + (lane << 3);
                glds16(src, xs2 + (size_t)(it * 256 + wv * 64) * 8);
            }
        }
    }
    asm volatile("s_waitcnt vmcnt(0)" ::: "memory");
    __syncthreads();

    for (int c = 0; c < 8; ++c) {
        _Float16* bcur = xs2 + (c & 1) * 19584;
        _Float16* bnxt = xs2 + ((c & 1) ^ 1) * 19584;
        const _Float16* wchunk = w16 + (size_t)(c * 4 + cb) * 18432;
        const _Float16* xcn = x16 + (size_t)(n * 8 + c + 1) * 131072;
        const bool pf = (c < 7);

        #pragma unroll
        for (int kx = 0; kx < 3; ++kx) {
            // A-fragments for this kx: [ks][ky][cob]
            half8 bf[2][3][2];
            #pragma unroll
            for (int ks = 0; ks < 2; ++ks)
                #pragma unroll
                for (int ky = 0; ky < 3; ++ky)
                    #pragma unroll
                    for (int cob = 0; cob < 2; ++cob)
                        bf[ks][ky][cob] = *(const half8*)&wchunk[
                            ((ky * 3 + kx) * 4 + ks * 2 + cob) * 512 + lane * 8];

            // early-issued staging of next chunk (5 iters after kx0, 5 after kx1)
            if (kx == 0 && pf) {
                SB();
                #pragma unroll
                for (int it = 0; it < 5; ++it) {
                    const _Float16* src = (soff[it] >= 0) ? xcn + soff[it] : zp + (lane << 3);
                    glds16(src, bnxt + (size_t)(it * 256 + wv * 64) * 8);
                }
                SB();
            }
            if (kx == 1 && pf) {
                SB();
                #pragma unroll
                for (int it = 5; it < 10; ++it) {
                    if (it * 256 + tid < 2448) {
                        const _Float16* src = (soff[it] >= 0) ? xcn + soff[it] : zp + (lane << 3);
                        glds16(src, bnxt + (size_t)(it * 256 + wv * 64) * 8);
                    }
                }
                SB();
            }

            #pragma unroll
            for (int ks = 0; ks < 2; ++ks) {
                // B-fragments: 6 staged rows cover ro+ky = 0..5 for this ks
                half8 af[6];
                #pragma unroll
                for (int rr = 0; rr < 6; ++rr)
                    af[rr] = *(const half8*)&bcur[
                        ((wv * 4 + rr) * 136 + ks * 68 + kx) * 8 + albase];
                __builtin_amdgcn_s_setprio(1);
                #pragma unroll
                for (int ky = 0; ky < 3; ++ky)         // same-acc reuse distance 8
                    #pragma unroll
                    for (int ro = 0; ro < 4; ++ro)
                        #pragma unroll
                        for (int cob = 0; cob < 2; ++cob)
                            acc[ro][cob] = __builtin_amdgcn_mfma_f32_32x32x16_f16(
                                bf[ks][ky][cob], af[ro + ky], acc[ro][cob], 0, 0, 0);
                __builtin_amdgcn_s_setprio(0);
            }
        }
        asm volatile("s_waitcnt vmcnt(0)" ::: "memory");
        __syncthreads();
    }

    // epilogue: fp16 y into upper half of each plane's 16KB slot in d_out
    // C/D 32x32 map: col = lane&31 (px w), row = (reg&3) + 8*(reg>>2) + 4*kh (co)
    _Float16* y16o = (_Float16*)y;
    #pragma unroll
    for (int cob = 0; cob < 2; ++cob) {
        #pragma unroll
        for (int reg = 0; reg < 16; ++reg) {
            const int co = cb * 64 + cob * 32 + (reg & 3) + 8 * (reg >> 2) + 4 * kh;
            _Float16* yp = y16o + (size_t)(n * COUT + co) * 8192 + 4096;
            #pragma unroll
            for (int ro = 0; ro < 4; ++ro)
                yp[(h0 + wv * 4 + ro) * 64 + w0 + l31] = (_Float16)acc[ro][cob][reg];
        }
    }
}

// ---------------------------------------------------------------------------
// Solve: Out = Gu * (Y * Gv^T), two fp16 MFMA GEMMs per plane.
// Block = (c, 4 consecutive n): G staged once, Y double-buffered via
// global_load_lds issued before GEMM1 of the previous plane. 40KB LDS,
// 4 blocks/CU. Final fp32 written over the plane slot.
// ---------------------------------------------------------------------------
__global__ __launch_bounds__(256, 4) void solve_mfma(const _Float16* __restrict__ gm,
                                                     float* __restrict__ y) {
    __shared__ __align__(16) _Float16 Ysd[2][64 * 64];
    __shared__ __align__(16) _Float16 Tt[64 * 64];
    __shared__ __align__(16) _Float16 Gsh[2 * 64 * 64];
    const int tid  = threadIdx.x;
    const int lane = tid & 63;
    const int wv   = tid >> 6;
    const int m    = lane & 15;
    const int q    = lane >> 4;
    const int bid  = blockIdx.x;        // 2048
    const int nq   = bid & 7;
    const int c    = bid >> 3;

    // stage G (already swizzled in ws)
    {
        const _Float16* gsrc = gm + (size_t)c * 8192;
        #pragma unroll
        for (int it = 0; it < 4; ++it)
            glds16(gsrc + (size_t)(it * 256 + tid) * 8, Gsh + (size_t)(it * 256 + wv * 64) * 8);
    }
    // stage Y plane 0 (fp16, pre-swizzled source -> linear LDS)
    {
        const _Float16* ysrc = (const _Float16*)y + ((size_t)(nq * 4 + 0) * 256 + c) * 8192 + 4096;
        #pragma unroll
        for (int it = 0; it < 2; ++it) {
            const int s  = it * 256 + tid;
            const int r  = s >> 3;
            const int kc = (s & 7) ^ (r & 7);
            glds16(ysrc + r * 64 + kc * 8, Ysd[0] + (size_t)(it * 256 + wv * 64) * 8);
        }
    }
    asm volatile("s_waitcnt vmcnt(0)" ::: "memory");
    __syncthreads();

    #pragma unroll
    for (int i = 0; i < 4; ++i) {
        const _Float16* Ys = Ysd[i & 1];
        if (i < 3) {   // prefetch Y of plane i+1 into the other buffer
            const _Float16* ysrc = (const _Float16*)y + ((size_t)(nq * 4 + i + 1) * 256 + c) * 8192 + 4096;
            #pragma unroll
            for (int it = 0; it < 2; ++it) {
                const int s  = it * 256 + tid;
                const int r  = s >> 3;
                const int kc = (s & 7) ^ (r & 7);
                glds16(ysrc + r * 64 + kc * 8, Ysd[(i & 1) ^ 1] + (size_t)(it * 256 + wv * 64) * 8);
            }
        }

        // GEMM1: T = Y * Gv^T ; lane holds T[16wv+q*4+r][u*16+m] -> write Tt[s][r]
        {
            floatx4 acc1[4];
            #pragma unroll
            for (int u = 0; u < 4; ++u) acc1[u] = (floatx4)0.f;
            #pragma unroll
            for (int ks = 0; ks < 2; ++ks) {
                const int swz = ((ks * 4 + q) ^ (m & 7)) * 8;
                const half8 yf = *(const half8*)&Ys[(16 * wv + m) * 64 + swz];
                #pragma unroll
                for (int u = 0; u < 4; ++u) {
                    const half8 gvf = *(const half8*)&Gsh[4096 + (u * 16 + m) * 64 + swz];
                    acc1[u] = __builtin_amdgcn_mfma_f32_16x16x32_f16(yf, gvf, acc1[u], 0, 0, 0);
                }
            }
            #pragma unroll
            for (int u = 0; u < 4; ++u) {
                half4 hv;
                #pragma unroll
                for (int r = 0; r < 4; ++r) hv[r] = (_Float16)acc1[u][r];
                const int s = u * 16 + m;
                const int kc = 2 * wv + (q >> 1);
                *(half4*)&Tt[s * 64 + ((kc ^ (s & 7)) * 8) + (q & 1) * 4] = hv;
            }
        }
        __syncthreads();

        // GEMM2: Out = Gu * T ; store fp32 in-place
        {
            float* yp = y + ((size_t)(nq * 4 + i) * 256 + c) * 4096;
            floatx4 acc2[4];
            #pragma unroll
            for (int u = 0; u < 4; ++u) acc2[u] = (floatx4)0.f;
            #pragma unroll
            for (int ks = 0; ks < 2; ++ks) {
                const int swz = ((ks * 4 + q) ^ (m & 7)) * 8;
                const half8 guf = *(const half8*)&Gsh[(16 * wv + m) * 64 + swz];
                #pragma unroll
                for (int u = 0; u < 4; ++u) {
                    const half8 ttf = *(const half8*)&Tt[(u * 16 + m) * 64 + swz];
                    acc2[u] = __builtin_amdgcn_mfma_f32_16x16x32_f16(guf, ttf, acc2[u], 0, 0, 0);
                }
            }
            #pragma unroll
            for (int u = 0; u < 4; ++u)
                #pragma unroll
                for (int r = 0; r < 4; ++r)
                    yp[(16 * wv + q * 4 + r) * 64 + u * 16 + m] = acc2[u][r];
        }
        if (i < 3) {
            asm volatile("s_waitcnt vmcnt(0)" ::: "memory");
            __syncthreads();
        }
    }
}

extern "C" void kernel_launch(void* const* d_in, const int* in_sizes, int n_in,
                              void* d_out, int out_size, void* d_ws, size_t ws_size,
                              hipStream_t stream) {
    const float* x     = (const float*)d_in[0];
    const float* w     = (const float*)d_in[1];
    const float* alpha = (const float*)d_in[2];
    float* y = (float*)d_out;

    // workspace layout (bytes)
    _Float16* x16 = (_Float16*)d_ws;                               // 67,108,864 B
    _Float16* w16 = (_Float16*)((char*)d_ws + 67108864);           //  1,179,648 B
    _Float16* gm  = (_Float16*)((char*)d_ws + 68288512);           //  4,194,304 B
    float*    gtab = (float*)((char*)d_ws + 72482816);             //    131,072 B
    float4*   zp   = (float4*)((char*)d_ws + 72613888);            //      4,096 B

    static bool inited = false;
    if (!inited) {
        hipFuncSetAttribute((const void*)conv_mfma,
                            hipFuncAttributeMaxDynamicSharedMemorySize, 78336);
        inited = true;
    }

    xprep_kernel <<<dim3(32 * 8 * 64), 256, 0, stream>>>(x, x16);
    wprep_kernel <<<dim3(2304),        256, 0, stream>>>(w, w16, zp);
    gprep1_kernel<<<dim3(128),         256, 0, stream>>>(alpha, gtab);
    gprep2_kernel<<<dim3(1024),        256, 0, stream>>>(gtab, gm);
    conv_mfma    <<<dim3(1024),        256, 78336, stream>>>(x16, w16, (const _Float16*)zp, y);
    solve_mfma   <<<dim3(2048),        256, 0, stream>>>(gm, y);
}

// Round 4
// 380.982 us; speedup vs baseline: 1.1061x; 1.1061x over previous
//
#include <hip/hip_runtime.h>
#include <cmath>
#include <stdint.h>

#define HH 64
#define WD 64
#define CIN 256
#define COUT 256
#define NB 32

typedef _Float16 half8 __attribute__((ext_vector_type(8)));
typedef _Float16 half4 __attribute__((ext_vector_type(4)));
typedef float floatx4 __attribute__((ext_vector_type(4)));
typedef float floatx16 __attribute__((ext_vector_type(16)));

#define SB() __builtin_amdgcn_sched_barrier(0)

__device__ __forceinline__ void glds16(const void* src, void* dst) {
    __builtin_amdgcn_global_load_lds((const __attribute__((address_space(1))) void*)src,
                                     (__attribute__((address_space(3))) void*)dst, 16, 0, 0);
}

// ---------------------------------------------------------------------------
// xprep: NCHW fp32 -> fp16 [n][chunk8][h64][w64][ci32]  (67 MB in ws)
// ---------------------------------------------------------------------------
__global__ __launch_bounds__(256) void xprep_kernel(const float* __restrict__ x,
                                                    _Float16* __restrict__ x16) {
    __shared__ _Float16 lt[32 * 72];
    const int tid = threadIdx.x;
    const int bid = blockIdx.x;           // n*512 + chunk*64 + h
    const int h = bid & 63;
    const int chunk = (bid >> 6) & 7;
    const int n = bid >> 9;
    {
        const int ci = tid >> 3;
        const int w8 = (tid & 7) * 8;
        const float* src = x + (((size_t)(n * 256 + chunk * 32 + ci) * 64 + h) * 64 + w8);
        const float4 a = *(const float4*)src;
        const float4 b = *(const float4*)(src + 4);
        half8 hv;
        hv[0] = (_Float16)a.x; hv[1] = (_Float16)a.y; hv[2] = (_Float16)a.z; hv[3] = (_Float16)a.w;
        hv[4] = (_Float16)b.x; hv[5] = (_Float16)b.y; hv[6] = (_Float16)b.z; hv[7] = (_Float16)b.w;
        *(half8*)&lt[ci * 72 + w8] = hv;
    }
    __syncthreads();
    {
        const int w = tid >> 2;
        const int kc = tid & 3;
        half8 hv;
        #pragma unroll
        for (int j = 0; j < 8; ++j) hv[j] = lt[(kc * 8 + j) * 72 + w];
        *(half8*)&x16[(((size_t)(n * 8 + chunk) * 64 + h) * 64 + w) * 32 + kc * 8] = hv;
    }
}

// ---------------------------------------------------------------------------
// wprep: w [co][ci][3][3] fp32 -> fp16 [chunk8][cb4][tap9][u4][q4][m16][j8]
// block 0 also zero-fills the 4KB zero page used for conv halo rows/cols.
// ---------------------------------------------------------------------------
__global__ __launch_bounds__(256) void wprep_kernel(const float* __restrict__ w,
                                                    _Float16* __restrict__ w16,
                                                    float4* __restrict__ zp) {
    const int idx = blockIdx.x * 256 + threadIdx.x;   // 589,824
    const int j = idx & 7;
    const int m = (idx >> 3) & 15;
    const int q = (idx >> 7) & 3;
    const int u = (idx >> 9) & 3;
    const int rest = idx >> 11;
    const int tap = rest % 9;
    const int rr = rest / 9;
    const int cb = rr & 3;
    const int chunk = rr >> 2;
    const int co = cb * 64 + u * 16 + m;
    const int ci = chunk * 32 + q * 8 + j;
    w16[idx] = (_Float16)w[(co * CIN + ci) * 9 + tap];
    if (blockIdx.x == 0) {
        float4 z; z.x = 0.f; z.y = 0.f; z.z = 0.f; z.w = 0.f;
        zp[threadIdx.x] = z;   // 4 KB of zeros
    }
}

// ---------------------------------------------------------------------------
// gprep (fused): per-channel circulant generators + expansion to swizzled
// fp16 circulant matrices.  One block per channel c.
// gm[c][which2][row64][kc8 ^ (row&7)][8],  G[row][col] = g[(row-col)&63]
// ---------------------------------------------------------------------------
__global__ __launch_bounds__(256) void gprep_kernel(const float* __restrict__ alpha,
                                                    _Float16* __restrict__ gm) {
    __shared__ float gl[128];
    const int c = blockIdx.x;     // 256
    const int tid = threadIdx.x;
    if (tid < 128) {
        const int r   = tid & 63;
        const int isv = tid >> 6;
        const float t0 = tanhf(alpha[c * 4 + isv * 2 + 0]);
        const float t1 = tanhf(alpha[c * 4 + isv * 2 + 1]);
        const float qq = 0.70710678118654752f;
        const float a0 = qq * (t0 + t1);   // tap -1
        const float a2 = qq * (t1 - t0);   // tap +1
        const float rev = 0.015625f;       // 1/64 revolution
        float ssum = 0.f;
        for (int p = 0; p < 64; ++p) {
            const float pr = (float)p * rev;
            const float re = 1.f + (a0 + a2) * __builtin_amdgcn_cosf(pr);
            const float im = (a0 - a2) * __builtin_amdgcn_sinf(pr);
            const float inv = 1.f / (re * re + im * im);
            const float ph = (float)((p * r) & 63) * rev;
            ssum += (__builtin_amdgcn_cosf(ph) * re + __builtin_amdgcn_sinf(ph) * im) * inv;
        }
        gl[tid] = ssum * (1.0f / 64.0f);
    }
    __syncthreads();
    #pragma unroll
    for (int it = 0; it < 4; ++it) {
        const int idx = it * 256 + tid;   // 0..1023 = which*512 + row*8 + kc
        const int kc = idx & 7;
        const int row = (idx >> 3) & 63;
        const int which = idx >> 9;
        const float* g = gl + which * 64;
        half8 hv;
        #pragma unroll
        for (int j = 0; j < 8; ++j)
            hv[j] = (_Float16)g[(row - (kc * 8 + j)) & 63];
        *(half8*)&gm[((size_t)(c * 2 + which) * 64 + row) * 64 + ((kc ^ (row & 7)) * 8)] = hv;
    }
}

// ---------------------------------------------------------------------------
// Conv 3x3 as implicit GEMM, fp16 MFMA 16x16x32 (round-2 version, 121 us).
// 256-thread block (4 waves), tile 64co x 16rows x 32cols.
// Wave: 64co x 4rows x 32px (acc 128 AGPR); ky-row-reuse: 6 staged rows feed
// 12 (ro,ky) pairs. LDS dbuf 2x39,168B -> 2 blocks/CU (barrier-decoupled).
// x staged via global_load_lds (16B slots, pre-swizzled source), issued early
// inside compute; one barrier per chunk; setprio around MFMA clusters.
// Output fp16 into upper half of each plane's fp32 slot in d_out.
// ---------------------------------------------------------------------------
__global__ __launch_bounds__(256, 2) void conv_mfma(const _Float16* __restrict__ x16,
                                                    const _Float16* __restrict__ w16,
                                                    const _Float16* __restrict__ zp,
                                                    float* __restrict__ y) {
    extern __shared__ __align__(16) _Float16 xs2[];   // 2 * 19,584 halfs = 78,336 B
    const int tid  = threadIdx.x;
    const int lane = tid & 63;
    const int wv   = tid >> 6;          // 0..3
    const int m    = lane & 15;
    const int q    = lane >> 4;

    // XCD-bijective remap: the 8 (cb,wt) blocks of one (n,ht) land on one XCD.
    const int bid  = blockIdx.x;        // 1024
    const int xcd  = bid & 7;
    const int idx  = bid >> 3;          // 0..127
    const int sub  = idx & 7;
    const int cb   = sub >> 1;          // 0..3
    const int wt   = sub & 1;           // 0..1
    const int pair = xcd * 16 + (idx >> 3);   // 0..127 = (ht,n)
    const int ht   = pair & 3;
    const int n    = pair >> 2;
    const int h0   = ht * 16;
    const int w0   = wt * 32;

    // staging: 2448 slots of 16B; slot = row*136 + col*4 + octp (rows 18, cols 34)
    // stored data = x[h0-1+row][w0-1+col][oct = octp ^ (col&3)]  (pre-swizzled src)
    int soff[10];
    #pragma unroll
    for (int it = 0; it < 10; ++it) {
        const int slot = it * 256 + tid;
        const int row  = (slot * 7711) >> 20;        // floor(slot/136), slot<2448
        const int rem  = slot - row * 136;
        const int col  = rem >> 2;
        const int oct  = (rem & 3) ^ (col & 3);
        const int gh   = h0 - 1 + row;
        const int gw   = w0 - 1 + col;
        soff[it] = ((unsigned)gh < 64u && (unsigned)gw < 64u)
                 ? ((gh * 64 + gw) * 32 + oct * 8) : -1;
    }

    // per-lane af column offset (halfs) per kx within (row, cbk=0)
    int aoff[3];
    #pragma unroll
    for (int kx = 0; kx < 3; ++kx)
        aoff[kx] = (m + kx) * 32 + ((q ^ ((m + kx) & 3)) * 8);

    floatx4 acc[4][2][4];
    #pragma unroll
    for (int ro = 0; ro < 4; ++ro)
        #pragma unroll
        for (int cbk = 0; cbk < 2; ++cbk)
            #pragma unroll
            for (int u = 0; u < 4; ++u) acc[ro][cbk][u] = (floatx4)0.f;

    // prologue: stage chunk 0 into buffer 0
    {
        const _Float16* xc0 = x16 + (size_t)n * 1048576;
        #pragma unroll
        for (int it = 0; it < 10; ++it) {
            if (it * 256 + tid < 2448) {
                const _Float16* src = (soff[it] >= 0) ? xc0 + soff[it] : zp + (lane << 3);
                glds16(src, xs2 + (size_t)(it * 256 + wv * 64) * 8);
            }
        }
    }
    asm volatile("s_waitcnt vmcnt(0)" ::: "memory");
    __syncthreads();

    for (int c = 0; c < 8; ++c) {
        _Float16* bcur = xs2 + (c & 1) * 19584;
        _Float16* bnxt = xs2 + ((c & 1) ^ 1) * 19584;
        const _Float16* wchunk = w16 + (size_t)(c * 4 + cb) * 18432;
        const _Float16* xcn = x16 + (size_t)(n * 8 + c + 1) * 131072;
        const bool pf = (c < 7);

        #pragma unroll
        for (int kx = 0; kx < 3; ++kx) {
            half8 bf[3][4];
            #pragma unroll
            for (int ky = 0; ky < 3; ++ky)
                #pragma unroll
                for (int u = 0; u < 4; ++u)
                    bf[ky][u] = *(const half8*)&wchunk[(ky * 3 + kx) * 2048 + u * 512 + lane * 8];

            // early-issued staging of next chunk (5 iters after kx0, 5 after kx1)
            if (kx == 0 && pf) {
                SB();
                #pragma unroll
                for (int it = 0; it < 5; ++it) {
                    const _Float16* src = (soff[it] >= 0) ? xcn + soff[it] : zp + (lane << 3);
                    glds16(src, bnxt + (size_t)(it * 256 + wv * 64) * 8);
                }
                SB();
            }
            if (kx == 1 && pf) {
                SB();
                #pragma unroll
                for (int it = 5; it < 10; ++it) {
                    if (it * 256 + tid < 2448) {
                        const _Float16* src = (soff[it] >= 0) ? xcn + soff[it] : zp + (lane << 3);
                        glds16(src, bnxt + (size_t)(it * 256 + wv * 64) * 8);
                    }
                }
                SB();
            }

            #pragma unroll
            for (int cbk = 0; cbk < 2; ++cbk) {
                half8 af[6];
                #pragma unroll
                for (int rr = 0; rr < 6; ++rr)
                    af[rr] = *(const half8*)&bcur[(wv * 4 + rr) * 1088 + cbk * 512 + aoff[kx]];
                __builtin_amdgcn_s_setprio(1);
                #pragma unroll
                for (int ro = 0; ro < 4; ++ro)
                    #pragma unroll
                    for (int ky = 0; ky < 3; ++ky)
                        #pragma unroll
                        for (int u = 0; u < 4; ++u)
                            acc[ro][cbk][u] = __builtin_amdgcn_mfma_f32_16x16x32_f16(
                                bf[ky][u], af[ro + ky], acc[ro][cbk][u], 0, 0, 0);
                __builtin_amdgcn_s_setprio(0);
            }
        }
        asm volatile("s_waitcnt vmcnt(0)" ::: "memory");
        __syncthreads();
    }

    // epilogue: fp16 y into upper half of each plane's 16KB slot in d_out
    _Float16* y16o = (_Float16*)y;
    #pragma unroll
    for (int u = 0; u < 4; ++u) {
        #pragma unroll
        for (int r = 0; r < 4; ++r) {
            const int co = cb * 64 + u * 16 + q * 4 + r;
            _Float16* yp = y16o + (size_t)(n * COUT + co) * 8192 + 4096;
            #pragma unroll
            for (int ro = 0; ro < 4; ++ro)
                #pragma unroll
                for (int cbk = 0; cbk < 2; ++cbk)
                    yp[(h0 + wv * 4 + ro) * 64 + w0 + cbk * 16 + m] = (_Float16)acc[ro][cbk][u][r];
        }
    }
}

// ---------------------------------------------------------------------------
// Solve v2: Out = Gu * (Y * Gv^T) with ONE WAVE PER PLANE — no inter-wave
// barriers after the G stage.  32x32x16 MFMA (mappings HW-verified by the
// round-3 conv).  Y A-frags read directly from global (fp16 region written
// by conv); T transposed through a per-wave 8KB LDS region with a wave-local
// lgkmcnt(0) only.  LDS 48KB/block.
// ---------------------------------------------------------------------------
__global__ __launch_bounds__(256, 3) void solve_mfma(const _Float16* __restrict__ gm,
                                                     float* __restrict__ y) {
    __shared__ __align__(16) _Float16 Gsh[2 * 64 * 64];   // 16 KB (Gu, Gv; swizzled)
    __shared__ __align__(16) _Float16 TT[4][64 * 64];     // 8 KB per wave: T^T swizzled
    const int tid  = threadIdx.x;
    const int lane = tid & 63;
    const int wv   = tid >> 6;
    const int l31  = lane & 31;
    const int kh   = lane >> 5;

    // XCD-major remap: the 8 nq-blocks of one c land on one XCD (G reuse in L2)
    const int bid = blockIdx.x;                 // 2048
    const int wg  = (bid & 7) * 256 + (bid >> 3);
    const int c   = wg >> 3;
    const int nq  = wg & 7;
    const int n   = nq * 4 + wv;                // this wave's plane

    // stage G (both matrices, swizzled layout preserved, linear copy)
    {
        const _Float16* gsrc = gm + (size_t)c * 8192;
        #pragma unroll
        for (int it = 0; it < 4; ++it)
            glds16(gsrc + (size_t)(it * 256 + tid) * 8, Gsh + (size_t)(it * 256 + wv * 64) * 8);
    }
    asm volatile("s_waitcnt vmcnt(0)" ::: "memory");
    __syncthreads();

    const _Float16* ysrc = (const _Float16*)y + ((size_t)n * 256 + c) * 8192 + 4096;
    float* yp = y + ((size_t)n * 256 + c) * 4096;
    _Float16* tt = TT[wv];

    // ---- GEMM1: T = Y * Gv^T  (A = Y rows, B = Gv rows) ----
    floatx16 a1[2][2];
    #pragma unroll
    for (int tr = 0; tr < 2; ++tr)
        #pragma unroll
        for (int tc = 0; tc < 2; ++tc) a1[tr][tc] = (floatx16)0.f;

    half8 yf[2][4];
    #pragma unroll
    for (int tr = 0; tr < 2; ++tr)
        #pragma unroll
        for (int ks = 0; ks < 4; ++ks)
            yf[tr][ks] = *(const half8*)&ysrc[(32 * tr + l31) * 64 + ks * 16 + kh * 8];

    #pragma unroll
    for (int ks = 0; ks < 4; ++ks) {
        const int kc = ks * 2 + kh;
        half8 gv[2];
        #pragma unroll
        for (int tc = 0; tc < 2; ++tc) {
            const int row = 32 * tc + l31;
            gv[tc] = *(const half8*)&Gsh[4096 + row * 64 + ((kc ^ (row & 7)) * 8)];
        }
        #pragma unroll
        for (int tr = 0; tr < 2; ++tr)
            #pragma unroll
            for (int tc = 0; tc < 2; ++tc)
                a1[tr][tc] = __builtin_amdgcn_mfma_f32_32x32x16_f16(
                    yf[tr][ks], gv[tc], a1[tr][tc], 0, 0, 0);
    }

    // ---- write T^T to per-wave LDS (swizzled), wave-local sync only ----
    // GEMM1 D map: T[32tr + (reg&3)+8*(reg>>2)+4*kh][32tc + l31]
    #pragma unroll
    for (int tr = 0; tr < 2; ++tr) {
        #pragma unroll
        for (int tc = 0; tc < 2; ++tc) {
            const int tcol = 32 * tc + l31;
            #pragma unroll
            for (int q2 = 0; q2 < 4; ++q2) {
                half4 hv;
                #pragma unroll
                for (int rq = 0; rq < 4; ++rq) hv[rq] = (_Float16)a1[tr][tc][q2 * 4 + rq];
                *(half4*)&tt[tcol * 64 + (((4 * tr + q2) ^ (tcol & 7)) * 8) + 4 * kh] = hv;
            }
        }
    }
    asm volatile("s_waitcnt lgkmcnt(0)" ::: "memory");
    __builtin_amdgcn_sched_barrier(0);

    // ---- GEMM2: Out = Gu * T  (A = Gu rows, B = T^T cols via tt) ----
    floatx16 a2[2][2];
    #pragma unroll
    for (int tr = 0; tr < 2; ++tr)
        #pragma unroll
        for (int tc = 0; tc < 2; ++tc) a2[tr][tc] = (floatx16)0.f;

    #pragma unroll
    for (int ks = 0; ks < 4; ++ks) {
        const int kc = ks * 2 + kh;
        half8 gu[2], tb[2];
        #pragma unroll
        for (int tr = 0; tr < 2; ++tr) {
            const int row = 32 * tr + l31;
            gu[tr] = *(const half8*)&Gsh[row * 64 + ((kc ^ (row & 7)) * 8)];
        }
        #pragma unroll
        for (int tc = 0; tc < 2; ++tc) {
            const int col = 32 * tc + l31;
            tb[tc] = *(const half8*)&tt[col * 64 + ((kc ^ (col & 7)) * 8)];
        }
        #pragma unroll
        for (int tr = 0; tr < 2; ++tr)
            #pragma unroll
            for (int tc = 0; tc < 2; ++tc)
                a2[tr][tc] = __builtin_amdgcn_mfma_f32_32x32x16_f16(
                    gu[tr], tb[tc], a2[tr][tc], 0, 0, 0);
    }

    // ---- epilogue: fp32 over the plane slot ----
    #pragma unroll
    for (int tr = 0; tr < 2; ++tr)
        #pragma unroll
        for (int tc = 0; tc < 2; ++tc)
            #pragma unroll
            for (int reg = 0; reg < 16; ++reg) {
                const int row = 32 * tr + (reg & 3) + 8 * (reg >> 2) + 4 * kh;
                yp[row * 64 + 32 * tc + l31] = a2[tr][tc][reg];
            }
}

extern "C" void kernel_launch(void* const* d_in, const int* in_sizes, int n_in,
                              void* d_out, int out_size, void* d_ws, size_t ws_size,
                              hipStream_t stream) {
    const float* x     = (const float*)d_in[0];
    const float* w     = (const float*)d_in[1];
    const float* alpha = (const float*)d_in[2];
    float* y = (float*)d_out;

    // workspace layout (bytes)
    _Float16* x16 = (_Float16*)d_ws;                               // 67,108,864 B
    _Float16* w16 = (_Float16*)((char*)d_ws + 67108864);           //  1,179,648 B
    _Float16* gm  = (_Float16*)((char*)d_ws + 68288512);           //  4,194,304 B
    float4*   zp   = (float4*)((char*)d_ws + 72613888);            //      4,096 B

    static bool inited = false;
    if (!inited) {
        hipFuncSetAttribute((const void*)conv_mfma,
                            hipFuncAttributeMaxDynamicSharedMemorySize, 78336);
        inited = true;
    }

    xprep_kernel <<<dim3(32 * 8 * 64), 256, 0, stream>>>(x, x16);
    wprep_kernel <<<dim3(2304),        256, 0, stream>>>(w, w16, zp);
    gprep_kernel <<<dim3(256),         256, 0, stream>>>(alpha, gm);
    conv_mfma    <<<dim3(1024),        256, 78336, stream>>>(x16, w16, (const _Float16*)zp, y);
    solve_mfma   <<<dim3(2048),        256, 0, stream>>>(gm, y);
}

// Round 5
// 375.196 us; speedup vs baseline: 1.1231x; 1.0154x over previous
//
#include <hip/hip_runtime.h>
#include <cmath>
#include <stdint.h>

#define HH 64
#define WD 64
#define CIN 256
#define COUT 256
#define NB 32

typedef _Float16 half8 __attribute__((ext_vector_type(8)));
typedef _Float16 half4 __attribute__((ext_vector_type(4)));
typedef float floatx4 __attribute__((ext_vector_type(4)));
typedef float floatx16 __attribute__((ext_vector_type(16)));

#define SB() __builtin_amdgcn_sched_barrier(0)

__device__ __forceinline__ void glds16(const void* src, void* dst) {
    __builtin_amdgcn_global_load_lds((const __attribute__((address_space(1))) void*)src,
                                     (__attribute__((address_space(3))) void*)dst, 16, 0, 0);
}

// x16 lives in the LOWER half of each 16KB plane slot of d_out.
// Linear x16 byte offset B (in [0, 64Mi)) maps to d_out byte M = B + (B & ~8191).
__device__ __forceinline__ unsigned xmap(unsigned B) {
    return B + (B & 0xFFFFE000u);
}

// ---------------------------------------------------------------------------
// Fused prep: blocks [0,16384) xprep, [16384,18688) wprep, [18688,18944) gprep.
//
// xprep: NCHW fp32 -> fp16 [n][chunk8][h64][w64][ci32] into d_out lower halves
// wprep: w [co][ci][3][3] fp32 -> fp16 [chunk8][cb4][tap9][u4][q4][m16][j8]
// gprep: circulant generators + expansion to swizzled fp16 matrices
// ---------------------------------------------------------------------------
__global__ __launch_bounds__(256) void prep_kernel(const float* __restrict__ x,
                                                   const float* __restrict__ w,
                                                   const float* __restrict__ alpha,
                                                   float* __restrict__ y,
                                                   _Float16* __restrict__ w16,
                                                   _Float16* __restrict__ gm,
                                                   float4* __restrict__ zp) {
    __shared__ _Float16 lt[32 * 72];
    __shared__ float gl[128];
    const int tid = threadIdx.x;
    const int bb = blockIdx.x;

    if (bb < 16384) {
        // ---------------- xprep ----------------
        const int h = bb & 63;
        const int chunk = (bb >> 6) & 7;
        const int n = bb >> 9;
        {
            const int ci = tid >> 3;
            const int w8 = (tid & 7) * 8;
            const float* src = x + (((size_t)(n * 256 + chunk * 32 + ci) * 64 + h) * 64 + w8);
            const float4 a = *(const float4*)src;
            const float4 b = *(const float4*)(src + 4);
            half8 hv;
            hv[0] = (_Float16)a.x; hv[1] = (_Float16)a.y; hv[2] = (_Float16)a.z; hv[3] = (_Float16)a.w;
            hv[4] = (_Float16)b.x; hv[5] = (_Float16)b.y; hv[6] = (_Float16)b.z; hv[7] = (_Float16)b.w;
            *(half8*)&lt[ci * 72 + w8] = hv;
        }
        __syncthreads();
        {
            const int wq = tid >> 2;
            const int kc = tid & 3;
            half8 hv;
            #pragma unroll
            for (int j = 0; j < 8; ++j) hv[j] = lt[(kc * 8 + j) * 72 + wq];
            const unsigned L = ((((unsigned)(n * 8 + chunk) * 64 + h) * 64 + wq) * 32 + kc * 8);
            const unsigned M = xmap(L * 2u);
            *(half8*)((char*)y + M) = hv;
        }
    } else if (bb < 16384 + 2304) {
        // ---------------- wprep ----------------
        const int idx = (bb - 16384) * 256 + tid;   // 589,824
        const int j = idx & 7;
        const int m = (idx >> 3) & 15;
        const int q = (idx >> 7) & 3;
        const int u = (idx >> 9) & 3;
        const int rest = idx >> 11;
        const int tap = rest % 9;
        const int rr = rest / 9;
        const int cb = rr & 3;
        const int chunk = rr >> 2;
        const int co = cb * 64 + u * 16 + m;
        const int ci = chunk * 32 + q * 8 + j;
        w16[idx] = (_Float16)w[(co * CIN + ci) * 9 + tap];
        if (bb == 16384) {
            float4 z; z.x = 0.f; z.y = 0.f; z.z = 0.f; z.w = 0.f;
            zp[tid] = z;   // 4 KB of zeros
        }
    } else {
        // ---------------- gprep ----------------
        const int c = bb - 18688;     // 0..255
        if (tid < 128) {
            const int r   = tid & 63;
            const int isv = tid >> 6;
            const float t0 = tanhf(alpha[c * 4 + isv * 2 + 0]);
            const float t1 = tanhf(alpha[c * 4 + isv * 2 + 1]);
            const float qq = 0.70710678118654752f;
            const float a0 = qq * (t0 + t1);   // tap -1
            const float a2 = qq * (t1 - t0);   // tap +1
            const float rev = 0.015625f;       // 1/64 revolution
            float ssum = 0.f;
            for (int p = 0; p < 64; ++p) {
                const float pr = (float)p * rev;
                const float re = 1.f + (a0 + a2) * __builtin_amdgcn_cosf(pr);
                const float im = (a0 - a2) * __builtin_amdgcn_sinf(pr);
                const float inv = 1.f / (re * re + im * im);
                const float ph = (float)((p * r) & 63) * rev;
                ssum += (__builtin_amdgcn_cosf(ph) * re + __builtin_amdgcn_sinf(ph) * im) * inv;
            }
            gl[tid] = ssum * (1.0f / 64.0f);
        }
        __syncthreads();
        #pragma unroll
        for (int it = 0; it < 4; ++it) {
            const int idx = it * 256 + tid;   // 0..1023 = which*512 + row*8 + kc
            const int kc = idx & 7;
            const int row = (idx >> 3) & 63;
            const int which = idx >> 9;
            const float* g = gl + which * 64;
            half8 hv;
            #pragma unroll
            for (int j = 0; j < 8; ++j)
                hv[j] = (_Float16)g[(row - (kc * 8 + j)) & 63];
            *(half8*)&gm[((size_t)(c * 2 + which) * 64 + row) * 64 + ((kc ^ (row & 7)) * 8)] = hv;
        }
    }
}

// ---------------------------------------------------------------------------
// Conv 3x3 as implicit GEMM, fp16 MFMA 16x16x32 (verified 124 us core).
// 256-thread block (4 waves), tile 64co x 16rows x 32cols.
// Wave: 64co x 4rows x 32px (acc 128 AGPR); ky-row-reuse: 6 staged rows feed
// 12 (ro,ky) pairs. LDS dbuf 2x39,168B -> 2 blocks/CU (barrier-decoupled).
// x16 read from d_out lower halves via xmap(); staged with global_load_lds
// (16B slots, pre-swizzled source), issued early inside compute; one barrier
// per chunk; setprio around MFMA clusters.
// Output fp16 into the UPPER half of each plane's 16KB slot in d_out.
// ---------------------------------------------------------------------------
__global__ __launch_bounds__(256, 2) void conv_mfma(const _Float16* __restrict__ w16,
                                                    const _Float16* __restrict__ zp,
                                                    float* __restrict__ y) {
    extern __shared__ __align__(16) _Float16 xs2[];   // 2 * 19,584 halfs = 78,336 B
    const int tid  = threadIdx.x;
    const int lane = tid & 63;
    const int wv   = tid >> 6;          // 0..3
    const int m    = lane & 15;
    const int q    = lane >> 4;

    // XCD-bijective remap: the 8 (cb,wt) blocks of one (n,ht) land on one XCD.
    const int bid  = blockIdx.x;        // 1024
    const int xcd  = bid & 7;
    const int idx  = bid >> 3;          // 0..127
    const int sub  = idx & 7;
    const int cb   = sub >> 1;          // 0..3
    const int wt   = sub & 1;           // 0..1
    const int pair = xcd * 16 + (idx >> 3);   // 0..127 = (ht,n)
    const int ht   = pair & 3;
    const int n    = pair >> 2;
    const int h0   = ht * 16;
    const int w0   = wt * 32;

    // staging: 2448 slots of 16B; slot = row*136 + col*4 + octp (rows 18, cols 34)
    // stored data = x[h0-1+row][w0-1+col][oct = octp ^ (col&3)]  (pre-swizzled src)
    // soffB[it] = BYTE offset within the chunk's linear x16 region, or -1.
    int soffB[10];
    #pragma unroll
    for (int it = 0; it < 10; ++it) {
        const int slot = it * 256 + tid;
        const int row  = (slot * 7711) >> 20;        // floor(slot/136), slot<2448
        const int rem  = slot - row * 136;
        const int col  = rem >> 2;
        const int oct  = (rem & 3) ^ (col & 3);
        const int gh   = h0 - 1 + row;
        const int gw   = w0 - 1 + col;
        soffB[it] = ((unsigned)gh < 64u && (unsigned)gw < 64u)
                 ? (((gh * 64 + gw) * 32 + oct * 8) * 2) : -1;
    }

    // per-lane af column offset (halfs) per kx within (row, cbk=0)
    int aoff[3];
    #pragma unroll
    for (int kx = 0; kx < 3; ++kx)
        aoff[kx] = (m + kx) * 32 + ((q ^ ((m + kx) & 3)) * 8);

    floatx4 acc[4][2][4];
    #pragma unroll
    for (int ro = 0; ro < 4; ++ro)
        #pragma unroll
        for (int cbk = 0; cbk < 2; ++cbk)
            #pragma unroll
            for (int u = 0; u < 4; ++u) acc[ro][cbk][u] = (floatx4)0.f;

    const char* yb = (const char*)y;

    // prologue: stage chunk 0 into buffer 0
    {
        const unsigned cbb0 = (unsigned)n * 2097152u;   // (n*8+0)*262144 bytes
        #pragma unroll
        for (int it = 0; it < 10; ++it) {
            if (it * 256 + tid < 2448) {
                const void* src = (soffB[it] >= 0)
                    ? (const void*)(yb + xmap(cbb0 + (unsigned)soffB[it]))
                    : (const void*)(zp + (lane << 3));
                glds16(src, xs2 + (size_t)(it * 256 + wv * 64) * 8);
            }
        }
    }
    asm volatile("s_waitcnt vmcnt(0)" ::: "memory");
    __syncthreads();

    for (int c = 0; c < 8; ++c) {
        _Float16* bcur = xs2 + (c & 1) * 19584;
        _Float16* bnxt = xs2 + ((c & 1) ^ 1) * 19584;
        const _Float16* wchunk = w16 + (size_t)(c * 4 + cb) * 18432;
        const unsigned cbbn = (unsigned)(n * 8 + c + 1) * 262144u;  // next-chunk byte base
        const bool pf = (c < 7);

        #pragma unroll
        for (int kx = 0; kx < 3; ++kx) {
            half8 bf[3][4];
            #pragma unroll
            for (int ky = 0; ky < 3; ++ky)
                #pragma unroll
                for (int u = 0; u < 4; ++u)
                    bf[ky][u] = *(const half8*)&wchunk[(ky * 3 + kx) * 2048 + u * 512 + lane * 8];

            // early-issued staging of next chunk (5 iters after kx0, 5 after kx1)
            if (kx == 0 && pf) {
                SB();
                #pragma unroll
                for (int it = 0; it < 5; ++it) {
                    const void* src = (soffB[it] >= 0)
                        ? (const void*)(yb + xmap(cbbn + (unsigned)soffB[it]))
                        : (const void*)(zp + (lane << 3));
                    glds16(src, bnxt + (size_t)(it * 256 + wv * 64) * 8);
                }
                SB();
            }
            if (kx == 1 && pf) {
                SB();
                #pragma unroll
                for (int it = 5; it < 10; ++it) {
                    if (it * 256 + tid < 2448) {
                        const void* src = (soffB[it] >= 0)
                            ? (const void*)(yb + xmap(cbbn + (unsigned)soffB[it]))
                            : (const void*)(zp + (lane << 3));
                        glds16(src, bnxt + (size_t)(it * 256 + wv * 64) * 8);
                    }
                }
                SB();
            }

            #pragma unroll
            for (int cbk = 0; cbk < 2; ++cbk) {
                half8 af[6];
                #pragma unroll
                for (int rr = 0; rr < 6; ++rr)
                    af[rr] = *(const half8*)&bcur[(wv * 4 + rr) * 1088 + cbk * 512 + aoff[kx]];
                __builtin_amdgcn_s_setprio(1);
                #pragma unroll
                for (int ro = 0; ro < 4; ++ro)
                    #pragma unroll
                    for (int ky = 0; ky < 3; ++ky)
                        #pragma unroll
                        for (int u = 0; u < 4; ++u)
                            acc[ro][cbk][u] = __builtin_amdgcn_mfma_f32_16x16x32_f16(
                                bf[ky][u], af[ro + ky], acc[ro][cbk][u], 0, 0, 0);
                __builtin_amdgcn_s_setprio(0);
            }
        }
        asm volatile("s_waitcnt vmcnt(0)" ::: "memory");
        __syncthreads();
    }

    // epilogue: fp16 y into upper half of each plane's 16KB slot in d_out
    _Float16* y16o = (_Float16*)y;
    #pragma unroll
    for (int u = 0; u < 4; ++u) {
        #pragma unroll
        for (int r = 0; r < 4; ++r) {
            const int co = cb * 64 + u * 16 + q * 4 + r;
            _Float16* yp = y16o + (size_t)(n * COUT + co) * 8192 + 4096;
            #pragma unroll
            for (int ro = 0; ro < 4; ++ro)
                #pragma unroll
                for (int cbk = 0; cbk < 2; ++cbk)
                    yp[(h0 + wv * 4 + ro) * 64 + w0 + cbk * 16 + m] = (_Float16)acc[ro][cbk][u][r];
        }
    }
}

// ---------------------------------------------------------------------------
// Solve: Out = Gu * (Y * Gv^T) with ONE WAVE PER PLANE — no inter-wave
// barriers after the G stage.  32x32x16 MFMA.  Y A-frags read directly from
// global (fp16 upper halves written by conv); T transposed through a per-wave
// 8KB LDS region with a wave-local lgkmcnt(0) only.  48KB LDS, 3 blocks/CU.
// ---------------------------------------------------------------------------
__global__ __launch_bounds__(256, 3) void solve_mfma(const _Float16* __restrict__ gm,
                                                     float* __restrict__ y) {
    __shared__ __align__(16) _Float16 Gsh[2 * 64 * 64];   // 16 KB (Gu, Gv; swizzled)
    __shared__ __align__(16) _Float16 TT[4][64 * 64];     // 8 KB per wave: T^T swizzled
    const int tid  = threadIdx.x;
    const int lane = tid & 63;
    const int wv   = tid >> 6;
    const int l31  = lane & 31;
    const int kh   = lane >> 5;

    // XCD-major remap: the 8 nq-blocks of one c land on one XCD (G reuse in L2)
    const int bid = blockIdx.x;                 // 2048
    const int wg  = (bid & 7) * 256 + (bid >> 3);
    const int c   = wg >> 3;
    const int nq  = wg & 7;
    const int n   = nq * 4 + wv;                // this wave's plane

    // stage G (both matrices, swizzled layout preserved, linear copy)
    {
        const _Float16* gsrc = gm + (size_t)c * 8192;
        #pragma unroll
        for (int it = 0; it < 4; ++it)
            glds16(gsrc + (size_t)(it * 256 + tid) * 8, Gsh + (size_t)(it * 256 + wv * 64) * 8);
    }
    asm volatile("s_waitcnt vmcnt(0)" ::: "memory");
    __syncthreads();

    const _Float16* ysrc = (const _Float16*)y + ((size_t)n * 256 + c) * 8192 + 4096;
    float* yp = y + ((size_t)n * 256 + c) * 4096;
    _Float16* tt = TT[wv];

    // ---- GEMM1: T = Y * Gv^T  (A = Y rows, B = Gv rows) ----
    floatx16 a1[2][2];
    #pragma unroll
    for (int tr = 0; tr < 2; ++tr)
        #pragma unroll
        for (int tc = 0; tc < 2; ++tc) a1[tr][tc] = (floatx16)0.f;

    half8 yf[2][4];
    #pragma unroll
    for (int tr = 0; tr < 2; ++tr)
        #pragma unroll
        for (int ks = 0; ks < 4; ++ks)
            yf[tr][ks] = *(const half8*)&ysrc[(32 * tr + l31) * 64 + ks * 16 + kh * 8];

    #pragma unroll
    for (int ks = 0; ks < 4; ++ks) {
        const int kc = ks * 2 + kh;
        half8 gv[2];
        #pragma unroll
        for (int tc = 0; tc < 2; ++tc) {
            const int row = 32 * tc + l31;
            gv[tc] = *(const half8*)&Gsh[4096 + row * 64 + ((kc ^ (row & 7)) * 8)];
        }
        #pragma unroll
        for (int tr = 0; tr < 2; ++tr)
            #pragma unroll
            for (int tc = 0; tc < 2; ++tc)
                a1[tr][tc] = __builtin_amdgcn_mfma_f32_32x32x16_f16(
                    yf[tr][ks], gv[tc], a1[tr][tc], 0, 0, 0);
    }

    // ---- write T^T to per-wave LDS (swizzled), wave-local sync only ----
    // GEMM1 D map: T[32tr + (reg&3)+8*(reg>>2)+4*kh][32tc + l31]
    #pragma unroll
    for (int tr = 0; tr < 2; ++tr) {
        #pragma unroll
        for (int tc = 0; tc < 2; ++tc) {
            const int tcol = 32 * tc + l31;
            #pragma unroll
            for (int q2 = 0; q2 < 4; ++q2) {
                half4 hv;
                #pragma unroll
                for (int rq = 0; rq < 4; ++rq) hv[rq] = (_Float16)a1[tr][tc][q2 * 4 + rq];
                *(half4*)&tt[tcol * 64 + (((4 * tr + q2) ^ (tcol & 7)) * 8) + 4 * kh] = hv;
            }
        }
    }
    asm volatile("s_waitcnt lgkmcnt(0)" ::: "memory");
    __builtin_amdgcn_sched_barrier(0);

    // ---- GEMM2: Out = Gu * T  (A = Gu rows, B = T^T cols via tt) ----
    floatx16 a2[2][2];
    #pragma unroll
    for (int tr = 0; tr < 2; ++tr)
        #pragma unroll
        for (int tc = 0; tc < 2; ++tc) a2[tr][tc] = (floatx16)0.f;

    #pragma unroll
    for (int ks = 0; ks < 4; ++ks) {
        const int kc = ks * 2 + kh;
        half8 gu[2], tb[2];
        #pragma unroll
        for (int tr = 0; tr < 2; ++tr) {
            const int row = 32 * tr + l31;
            gu[tr] = *(const half8*)&Gsh[row * 64 + ((kc ^ (row & 7)) * 8)];
        }
        #pragma unroll
        for (int tc = 0; tc < 2; ++tc) {
            const int col = 32 * tc + l31;
            tb[tc] = *(const half8*)&tt[col * 64 + ((kc ^ (col & 7)) * 8)];
        }
        #pragma unroll
        for (int tr = 0; tr < 2; ++tr)
            #pragma unroll
            for (int tc = 0; tc < 2; ++tc)
                a2[tr][tc] = __builtin_amdgcn_mfma_f32_32x32x16_f16(
                    gu[tr], tb[tc], a2[tr][tc], 0, 0, 0);
    }

    // ---- epilogue: fp32 over the plane slot ----
    #pragma unroll
    for (int tr = 0; tr < 2; ++tr)
        #pragma unroll
        for (int tc = 0; tc < 2; ++tc)
            #pragma unroll
            for (int reg = 0; reg < 16; ++reg) {
                const int row = 32 * tr + (reg & 3) + 8 * (reg >> 2) + 4 * kh;
                yp[row * 64 + 32 * tc + l31] = a2[tr][tc][reg];
            }
}

extern "C" void kernel_launch(void* const* d_in, const int* in_sizes, int n_in,
                              void* d_out, int out_size, void* d_ws, size_t ws_size,
                              hipStream_t stream) {
    const float* x     = (const float*)d_in[0];
    const float* w     = (const float*)d_in[1];
    const float* alpha = (const float*)d_in[2];
    float* y = (float*)d_out;

    // workspace layout (bytes) — 5.4 MB total
    _Float16* w16 = (_Float16*)d_ws;                               // 1,179,648 B
    _Float16* gm  = (_Float16*)((char*)d_ws + 1179648);            // 4,194,304 B
    float4*   zp  = (float4*)((char*)d_ws + 5373952);              //     4,096 B

    static bool inited = false;
    if (!inited) {
        hipFuncSetAttribute((const void*)conv_mfma,
                            hipFuncAttributeMaxDynamicSharedMemorySize, 78336);
        inited = true;
    }

    prep_kernel  <<<dim3(18944), 256, 0, stream>>>(x, w, alpha, y, w16, gm, zp);
    conv_mfma    <<<dim3(1024),  256, 78336, stream>>>(w16, (const _Float16*)zp, y);
    solve_mfma   <<<dim3(2048),  256, 0, stream>>>(gm, y);
}